// Round 1
// baseline (2531.775 us; speedup 1.0000x reference)
//
#include <hip/hip_runtime.h>

#define IN_SIZE 128
#define HID 256
#define N_SRC1 500000
#define N_DST1 100000
#define E1 1600000
#define N_DST2 16384
#define E2 262144

// ---------------- workspace layout (bytes) ----------------
// msg1: [N_DST1][128] f32   @ 0                (51,200,000)
// deg1: [N_DST1] f32        @ 51,200,000       (400,000)
// msg2: [N_DST2][256] f32   @ 51,600,128       (16,777,216)
// deg2: [N_DST2] f32        @ 68,377,344       (65,536)
// h:    [N_DST1][256] f32   @ 68,442,880       (102,400,000)
// total 170,842,880 bytes
#define OFF_MSG1 0ull
#define OFF_DEG1 51200000ull
#define OFF_MSG2 51600128ull
#define OFF_DEG2 68377344ull
#define OFF_H    68442880ull

// Scatter layer 1: 4 edges per 256-thread block, 64 lanes/edge, float2 each.
__global__ __launch_bounds__(256) void k_scatter1(
    const float* __restrict__ x, const int* __restrict__ src,
    const int* __restrict__ dst, float* __restrict__ msg,
    float* __restrict__ deg)
{
    const int e = blockIdx.x * 4 + (threadIdx.x >> 6);
    const int lane = threadIdx.x & 63;
    const int s = src[e];
    const int d = dst[e];
    const float2 v = *(const float2*)(x + (size_t)s * IN_SIZE + lane * 2);
    float* mp = msg + (size_t)d * IN_SIZE + lane * 2;
    atomicAdd(mp + 0, v.x);
    atomicAdd(mp + 1, v.y);
    if (lane == 0) atomicAdd(deg + d, 1.0f);
}

// Scatter layer 2: 4 edges per block, 64 lanes/edge, float4 each (256 cols).
__global__ __launch_bounds__(256) void k_scatter2(
    const float* __restrict__ h, const int* __restrict__ src,
    const int* __restrict__ dst, float* __restrict__ msg,
    float* __restrict__ deg)
{
    const int e = blockIdx.x * 4 + (threadIdx.x >> 6);
    const int lane = threadIdx.x & 63;
    const int s = src[e];
    const int d = dst[e];
    const float4 v = *(const float4*)(h + (size_t)s * HID + lane * 4);
    float* mp = msg + (size_t)d * HID + lane * 4;
    atomicAdd(mp + 0, v.x);
    atomicAdd(mp + 1, v.y);
    atomicAdd(mp + 2, v.z);
    atomicAdd(mp + 3, v.w);
    if (lane == 0) atomicAdd(deg + d, 1.0f);
}

// Fused SAGE layer GEMM: out[i,:] = act( A1[i,:]@W1 + (A2[i,:]/max(deg[i],1))@W2 + b )
// Block = 256 threads, tile = 32 rows x 256 cols. Wave w owns rows w*8..w*8+7
// (LDS reads are same-address broadcasts => conflict-free). Thread owns 4
// consecutive cols; 8x4 f32 register tile; W read as float4 from global (L2).
template<int K1, int K2>
__global__ __launch_bounds__(256) void k_gemm_fused(
    const float* __restrict__ A1,   // [M][K1]
    const float* __restrict__ A2,   // [M][K2] (pre-division message sums)
    const float* __restrict__ deg,  // [M]
    const float* __restrict__ W1,   // [K1][HID]
    const float* __restrict__ W2,   // [K2][HID]
    const float* __restrict__ bias, // [HID]
    float* __restrict__ out,        // [M][HID]
    const int do_relu)
{
    constexpr int KTOT = K1 + K2;
    __shared__ float At[32][KTOT + 4];

    const int tid = threadIdx.x;
    const int i0 = blockIdx.x * 32;

    // ---- stage A-tile: cols [0,K1) from A1, [K1,KTOT) from A2 * (1/deg) ----
    {
        const int r = tid >> 3;        // 0..31
        const int jb = tid & 7;        // 8 threads cooperate per row
        const int i = i0 + r;
        const float idg = 1.0f / fmaxf(deg[i], 1.0f);
        #pragma unroll
        for (int it = 0; it < KTOT / 32; ++it) {
            const int k = (jb + it * 8) * 4;
            float4 v;
            if (k < K1) {
                v = *(const float4*)(A1 + (size_t)i * K1 + k);
            } else {
                v = *(const float4*)(A2 + (size_t)i * K2 + (k - K1));
                v.x *= idg; v.y *= idg; v.z *= idg; v.w *= idg;
            }
            *(float4*)&At[r][k] = v;
        }
    }
    __syncthreads();

    const int rg = tid >> 6;            // wave id = row group
    const int c0 = (tid & 63) * 4;      // col base
    float acc[8][4];
    #pragma unroll
    for (int r = 0; r < 8; ++r)
        acc[r][0] = acc[r][1] = acc[r][2] = acc[r][3] = 0.0f;

    #pragma unroll 2
    for (int kb = 0; kb < KTOT; kb += 4) {
        const float* Wp = (kb < K1) ? (W1 + (size_t)kb * HID)
                                    : (W2 + (size_t)(kb - K1) * HID);
        const float4 w0 = *(const float4*)(Wp + 0 * HID + c0);
        const float4 w1 = *(const float4*)(Wp + 1 * HID + c0);
        const float4 w2 = *(const float4*)(Wp + 2 * HID + c0);
        const float4 w3 = *(const float4*)(Wp + 3 * HID + c0);
        #pragma unroll
        for (int r = 0; r < 8; ++r) {
            const float4 a = *(const float4*)&At[rg * 8 + r][kb];
            acc[r][0] += a.x * w0.x; acc[r][1] += a.x * w0.y;
            acc[r][2] += a.x * w0.z; acc[r][3] += a.x * w0.w;
            acc[r][0] += a.y * w1.x; acc[r][1] += a.y * w1.y;
            acc[r][2] += a.y * w1.z; acc[r][3] += a.y * w1.w;
            acc[r][0] += a.z * w2.x; acc[r][1] += a.z * w2.y;
            acc[r][2] += a.z * w2.z; acc[r][3] += a.z * w2.w;
            acc[r][0] += a.w * w3.x; acc[r][1] += a.w * w3.y;
            acc[r][2] += a.w * w3.z; acc[r][3] += a.w * w3.w;
        }
    }

    const float4 bv = *(const float4*)(bias + c0);
    #pragma unroll
    for (int r = 0; r < 8; ++r) {
        float4 o;
        o.x = acc[r][0] + bv.x;
        o.y = acc[r][1] + bv.y;
        o.z = acc[r][2] + bv.z;
        o.w = acc[r][3] + bv.w;
        if (do_relu) {
            o.x = fmaxf(o.x, 0.0f); o.y = fmaxf(o.y, 0.0f);
            o.z = fmaxf(o.z, 0.0f); o.w = fmaxf(o.w, 0.0f);
        }
        *(float4*)(out + (size_t)(i0 + rg * 8 + r) * HID + c0) = o;
    }
}

extern "C" void kernel_launch(void* const* d_in, const int* in_sizes, int n_in,
                              void* d_out, int out_size, void* d_ws, size_t ws_size,
                              hipStream_t stream) {
    const float* x       = (const float*)d_in[0];
    const int*   src1    = (const int*)d_in[1];
    const int*   dst1    = (const int*)d_in[2];
    const int*   src2    = (const int*)d_in[3];
    const int*   dst2    = (const int*)d_in[4];
    const float* W_self1 = (const float*)d_in[5];
    const float* W_neigh1= (const float*)d_in[6];
    const float* b1      = (const float*)d_in[7];
    const float* W_self2 = (const float*)d_in[8];
    const float* W_neigh2= (const float*)d_in[9];
    const float* b2      = (const float*)d_in[10];
    float* out = (float*)d_out;

    char* ws = (char*)d_ws;
    float* msg1 = (float*)(ws + OFF_MSG1);
    float* deg1 = (float*)(ws + OFF_DEG1);
    float* msg2 = (float*)(ws + OFF_MSG2);
    float* deg2 = (float*)(ws + OFF_DEG2);
    float* h    = (float*)(ws + OFF_H);

    // zero all accumulators (msg1, deg1, msg2, deg2) in one async memset
    hipMemsetAsync(d_ws, 0, OFF_H, stream);

    // layer 1 aggregation: 1.6M edges, 4 edges per 256-thread block
    k_scatter1<<<E1 / 4, 256, 0, stream>>>(x, src1, dst1, msg1, deg1);

    // layer 1 fused GEMM + ReLU: h = relu(x[:100000]@Wself1 + (msg1/deg1)@Wneigh1 + b1)
    k_gemm_fused<IN_SIZE, IN_SIZE><<<N_DST1 / 32, 256, 0, stream>>>(
        x, msg1, deg1, W_self1, W_neigh1, b1, h, 1);

    // layer 2 aggregation: 262144 edges
    k_scatter2<<<E2 / 4, 256, 0, stream>>>(h, src2, dst2, msg2, deg2);

    // layer 2 fused GEMM (no relu): out = h[:16384]@Wself2 + (msg2/deg2)@Wneigh2 + b2
    k_gemm_fused<HID, HID><<<N_DST2 / 32, 256, 0, stream>>>(
        h, msg2, deg2, W_self2, W_neigh2, b2, out, 0);
}

// Round 2
// 677.925 us; speedup vs baseline: 3.7346x; 3.7346x over previous
//
#include <hip/hip_runtime.h>

#define IN_SIZE 128
#define HID 256
#define N_SRC1 500000
#define N_DST1 100000
#define E1 1600000
#define N_DST2 16384
#define E2 262144

// ---------------- workspace layout (bytes) ----------------
// Lifetime-overlapped to stay within the proven-safe 170.84 MB footprint:
//   h    [100000][256] f32 @ 0           (102,400,000)  live: gemm1 -> end
//     layer-1 CSR scratch lives INSIDE h (dead before gemm1 writes h):
//       rp1  @ 0         (400,128)
//       cur1 @ 400,128   (400,128)
//       prt1 @ 800,256   (4,096)
//       csr1 @ 804,352   (6,400,000)   -> ends 7,204,352
//   msg1 [100000][128] f32 @ 102,400,000 (51,200,000)   live: pull1 -> gemm1
//     layer-2 CSR scratch lives INSIDE msg1 (built after gemm1):
//       rp2  @ +0        (65,664)
//       cur2 @ +65,664   (65,664)
//       prt2 @ +131,328  (4,096)
//       csr2 @ +135,424  (1,048,576)
//   msg2 [16384][256] f32 @ 153,600,000 (16,777,216)    -> ends 170,377,216
#define OFF_H    0ull
#define OFF_MSG1 102400000ull
#define OFF_MSG2 153600000ull

// ---------------- CSR build ----------------
__global__ __launch_bounds__(256) void k_hist(const int* __restrict__ dst,
                                              int* __restrict__ cnt, int n_edges) {
    for (int e = blockIdx.x * 256 + threadIdx.x; e < n_edges; e += gridDim.x * 256)
        atomicAdd(&cnt[dst[e]], 1);
}

// per-block sum of 256 degrees -> part[b]
__global__ __launch_bounds__(256) void k_scan_part(const int* __restrict__ deg,
                                                   int* __restrict__ part, int n) {
    __shared__ int s[256];
    const int tid = threadIdx.x;
    const int gid = blockIdx.x * 256 + tid;
    s[tid] = (gid < n) ? deg[gid] : 0;
    __syncthreads();
    for (int off = 128; off > 0; off >>= 1) {
        if (tid < off) s[tid] += s[tid + off];
        __syncthreads();
    }
    if (tid == 0) part[blockIdx.x] = s[0];
}

// serial exclusive scan of block partials (nblk <= 1024, trivially fast)
__global__ void k_scan_mid(int* __restrict__ part, int nblk) {
    if (threadIdx.x == 0 && blockIdx.x == 0) {
        int run = 0;
        for (int b = 0; b < nblk; ++b) { int t = part[b]; part[b] = run; run += t; }
    }
}

// exclusive scan within block + block offset; writes rowptr[i] and cur[i]
__global__ __launch_bounds__(256) void k_scan_final(int* __restrict__ degcur,
                                                    int* __restrict__ rowptr,
                                                    const int* __restrict__ part, int n) {
    __shared__ int s[256];
    const int tid = threadIdx.x;
    const int gid = blockIdx.x * 256 + tid;
    const int v = (gid < n) ? degcur[gid] : 0;
    s[tid] = v;
    __syncthreads();
    // Hillis-Steele inclusive scan
    for (int off = 1; off < 256; off <<= 1) {
        int t = (tid >= off) ? s[tid - off] : 0;
        __syncthreads();
        s[tid] += t;
        __syncthreads();
    }
    const int incl = s[tid];
    const int excl = incl - v;
    const int base = part[blockIdx.x];
    if (gid < n) { rowptr[gid] = base + excl; degcur[gid] = base + excl; }
    if (gid == n - 1) rowptr[n] = base + incl;
}

__global__ __launch_bounds__(256) void k_fill(const int* __restrict__ src,
                                              const int* __restrict__ dst,
                                              int* __restrict__ cur,
                                              int* __restrict__ csr, int n_edges) {
    for (int e = blockIdx.x * 256 + threadIdx.x; e < n_edges; e += gridDim.x * 256) {
        const int pos = atomicAdd(&cur[dst[e]], 1);
        csr[pos] = src[e];
    }
}

// ---------------- pull aggregation (mean) ----------------
// one wave per dst node; 64 lanes x float2 = 128 cols
__global__ __launch_bounds__(256) void k_pull_mean128(
    const float* __restrict__ x, const int* __restrict__ rp,
    const int* __restrict__ csr, float* __restrict__ msg, int n_dst) {
    const int d = blockIdx.x * 4 + (threadIdx.x >> 6);
    const int lane = threadIdx.x & 63;
    const int beg = rp[d], end = rp[d + 1];
    float ax = 0.0f, ay = 0.0f;
    const float* xb = x + (size_t)lane * 2;
    int j = beg;
    for (; j + 1 < end; j += 2) {
        const int s0 = csr[j], s1 = csr[j + 1];
        const float2 a = *(const float2*)(xb + (size_t)s0 * IN_SIZE);
        const float2 b = *(const float2*)(xb + (size_t)s1 * IN_SIZE);
        ax += a.x + b.x; ay += a.y + b.y;
    }
    if (j < end) {
        const float2 a = *(const float2*)(xb + (size_t)csr[j] * IN_SIZE);
        ax += a.x; ay += a.y;
    }
    const float inv = 1.0f / fmaxf((float)(end - beg), 1.0f);
    *(float2*)(msg + (size_t)d * IN_SIZE + lane * 2) = make_float2(ax * inv, ay * inv);
}

// one wave per dst node; 64 lanes x float4 = 256 cols
__global__ __launch_bounds__(256) void k_pull_mean256(
    const float* __restrict__ h, const int* __restrict__ rp,
    const int* __restrict__ csr, float* __restrict__ msg, int n_dst) {
    const int d = blockIdx.x * 4 + (threadIdx.x >> 6);
    const int lane = threadIdx.x & 63;
    const int beg = rp[d], end = rp[d + 1];
    float ax = 0.0f, ay = 0.0f, az = 0.0f, aw = 0.0f;
    const float* hb = h + (size_t)lane * 4;
    int j = beg;
    for (; j + 1 < end; j += 2) {
        const int s0 = csr[j], s1 = csr[j + 1];
        const float4 a = *(const float4*)(hb + (size_t)s0 * HID);
        const float4 b = *(const float4*)(hb + (size_t)s1 * HID);
        ax += a.x + b.x; ay += a.y + b.y; az += a.z + b.z; aw += a.w + b.w;
    }
    if (j < end) {
        const float4 a = *(const float4*)(hb + (size_t)csr[j] * HID);
        ax += a.x; ay += a.y; az += a.z; aw += a.w;
    }
    const float inv = 1.0f / fmaxf((float)(end - beg), 1.0f);
    float4 o; o.x = ax * inv; o.y = ay * inv; o.z = az * inv; o.w = aw * inv;
    *(float4*)(msg + (size_t)d * HID + lane * 4) = o;
}

// ---------------- fused layer GEMM ----------------
// out[i,:] = act( A1[i,:]@W1 + A2[i,:]@W2 + b )   (A2 already mean-normalized)
// Block = 256 threads, tile = 32 rows x 256 cols; wave w owns rows w*8..w*8+7
// (LDS reads are same-address broadcasts => conflict-free).
template<int K1, int K2>
__global__ __launch_bounds__(256) void k_gemm_fused(
    const float* __restrict__ A1,   // [M][K1]
    const float* __restrict__ A2,   // [M][K2]
    const float* __restrict__ W1,   // [K1][HID]
    const float* __restrict__ W2,   // [K2][HID]
    const float* __restrict__ bias, // [HID]
    float* __restrict__ out,        // [M][HID]
    const int do_relu)
{
    constexpr int KTOT = K1 + K2;
    __shared__ float At[32][KTOT + 4];

    const int tid = threadIdx.x;
    const int i0 = blockIdx.x * 32;

    {
        const int r = tid >> 3;        // 0..31
        const int jb = tid & 7;        // 8 threads per row
        const int i = i0 + r;
        #pragma unroll
        for (int it = 0; it < KTOT / 32; ++it) {
            const int k = (jb + it * 8) * 4;
            float4 v;
            if (k < K1) v = *(const float4*)(A1 + (size_t)i * K1 + k);
            else        v = *(const float4*)(A2 + (size_t)i * K2 + (k - K1));
            *(float4*)&At[r][k] = v;
        }
    }
    __syncthreads();

    const int rg = tid >> 6;
    const int c0 = (tid & 63) * 4;
    float acc[8][4];
    #pragma unroll
    for (int r = 0; r < 8; ++r)
        acc[r][0] = acc[r][1] = acc[r][2] = acc[r][3] = 0.0f;

    #pragma unroll 2
    for (int kb = 0; kb < KTOT; kb += 4) {
        const float* Wp = (kb < K1) ? (W1 + (size_t)kb * HID)
                                    : (W2 + (size_t)(kb - K1) * HID);
        const float4 w0 = *(const float4*)(Wp + 0 * HID + c0);
        const float4 w1 = *(const float4*)(Wp + 1 * HID + c0);
        const float4 w2 = *(const float4*)(Wp + 2 * HID + c0);
        const float4 w3 = *(const float4*)(Wp + 3 * HID + c0);
        #pragma unroll
        for (int r = 0; r < 8; ++r) {
            const float4 a = *(const float4*)&At[rg * 8 + r][kb];
            acc[r][0] += a.x * w0.x; acc[r][1] += a.x * w0.y;
            acc[r][2] += a.x * w0.z; acc[r][3] += a.x * w0.w;
            acc[r][0] += a.y * w1.x; acc[r][1] += a.y * w1.y;
            acc[r][2] += a.y * w1.z; acc[r][3] += a.y * w1.w;
            acc[r][0] += a.z * w2.x; acc[r][1] += a.z * w2.y;
            acc[r][2] += a.z * w2.z; acc[r][3] += a.z * w2.w;
            acc[r][0] += a.w * w3.x; acc[r][1] += a.w * w3.y;
            acc[r][2] += a.w * w3.z; acc[r][3] += a.w * w3.w;
        }
    }

    const float4 bv = *(const float4*)(bias + c0);
    #pragma unroll
    for (int r = 0; r < 8; ++r) {
        float4 o;
        o.x = acc[r][0] + bv.x;
        o.y = acc[r][1] + bv.y;
        o.z = acc[r][2] + bv.z;
        o.w = acc[r][3] + bv.w;
        if (do_relu) {
            o.x = fmaxf(o.x, 0.0f); o.y = fmaxf(o.y, 0.0f);
            o.z = fmaxf(o.z, 0.0f); o.w = fmaxf(o.w, 0.0f);
        }
        *(float4*)(out + (size_t)(i0 + rg * 8 + r) * HID + c0) = o;
    }
}

extern "C" void kernel_launch(void* const* d_in, const int* in_sizes, int n_in,
                              void* d_out, int out_size, void* d_ws, size_t ws_size,
                              hipStream_t stream) {
    const float* x       = (const float*)d_in[0];
    const int*   src1    = (const int*)d_in[1];
    const int*   dst1    = (const int*)d_in[2];
    const int*   src2    = (const int*)d_in[3];
    const int*   dst2    = (const int*)d_in[4];
    const float* W_self1 = (const float*)d_in[5];
    const float* W_neigh1= (const float*)d_in[6];
    const float* b1      = (const float*)d_in[7];
    const float* W_self2 = (const float*)d_in[8];
    const float* W_neigh2= (const float*)d_in[9];
    const float* b2      = (const float*)d_in[10];
    float* out = (float*)d_out;

    char* ws = (char*)d_ws;
    float* h    = (float*)(ws + OFF_H);
    float* msg1 = (float*)(ws + OFF_MSG1);
    float* msg2 = (float*)(ws + OFF_MSG2);

    // layer-1 CSR scratch inside h region (dead before gemm1 writes h)
    int* rp1  = (int*)(ws + OFF_H + 0);
    int* cur1 = (int*)(ws + OFF_H + 400128);
    int* prt1 = (int*)(ws + OFF_H + 800256);
    int* csr1 = (int*)(ws + OFF_H + 804352);
    // layer-2 CSR scratch inside msg1 region (built after gemm1)
    int* rp2  = (int*)(ws + OFF_MSG1 + 0);
    int* cur2 = (int*)(ws + OFF_MSG1 + 65664);
    int* prt2 = (int*)(ws + OFF_MSG1 + 131328);
    int* csr2 = (int*)(ws + OFF_MSG1 + 135424);

    const int nblk1 = (N_DST1 + 255) / 256;   // 391
    const int nblk2 = (N_DST2 + 255) / 256;   // 64

    // ---- layer 1: build CSR, pull, GEMM ----
    hipMemsetAsync(cur1, 0, N_DST1 * sizeof(int), stream);
    k_hist<<<2048, 256, 0, stream>>>(dst1, cur1, E1);
    k_scan_part<<<nblk1, 256, 0, stream>>>(cur1, prt1, N_DST1);
    k_scan_mid<<<1, 64, 0, stream>>>(prt1, nblk1);
    k_scan_final<<<nblk1, 256, 0, stream>>>(cur1, rp1, prt1, N_DST1);
    k_fill<<<2048, 256, 0, stream>>>(src1, dst1, cur1, csr1, E1);
    k_pull_mean128<<<N_DST1 / 4, 256, 0, stream>>>(x, rp1, csr1, msg1, N_DST1);
    k_gemm_fused<IN_SIZE, IN_SIZE><<<N_DST1 / 32, 256, 0, stream>>>(
        x, msg1, W_self1, W_neigh1, b1, h, 1);

    // ---- layer 2: build CSR (msg1 now dead), pull, GEMM ----
    hipMemsetAsync(cur2, 0, N_DST2 * sizeof(int), stream);
    k_hist<<<1024, 256, 0, stream>>>(dst2, cur2, E2);
    k_scan_part<<<nblk2, 256, 0, stream>>>(cur2, prt2, N_DST2);
    k_scan_mid<<<1, 64, 0, stream>>>(prt2, nblk2);
    k_scan_final<<<nblk2, 256, 0, stream>>>(cur2, rp2, prt2, N_DST2);
    k_fill<<<1024, 256, 0, stream>>>(src2, dst2, cur2, csr2, E2);
    k_pull_mean256<<<N_DST2 / 4, 256, 0, stream>>>(h, rp2, csr2, msg2, N_DST2);
    k_gemm_fused<HID, HID><<<N_DST2 / 32, 256, 0, stream>>>(
        h, msg2, W_self2, W_neigh2, b2, out, 0);
}

// Round 3
// 548.366 us; speedup vs baseline: 4.6169x; 1.2363x over previous
//
#include <hip/hip_runtime.h>

#define IN_SIZE 128
#define HID 256
#define N_SRC1 500000
#define N_DST1 100000
#define E1 1600000
#define N_DST2 16384
#define E2 262144

// ---------------- workspace layout (bytes), total 93,970,176 ----------------
#define OFF_H     0ull          // h    [100000][256] bf16  (51,200,000)
#define OFF_MSG1  51200000ull   // msg1 [100000][128] bf16  (25,600,000)
#define OFF_MSG2  76800000ull   // msg2 [16384][256]  bf16  (8,388,608)
#define OFF_RP1   85188608ull   // rowptr1 [100001] i32     (400,128 alloc)
#define OFF_CUR1  85588736ull   // cursor1 [100000] i32     (400,128 alloc)
#define OFF_PRT1  85988864ull   // partials [<=1024] i32    (4,096)
#define OFF_CSR1  85992960ull   // csr1 [1,600,000] i32     (6,400,000)
#define OFF_RP2   92392960ull   // rowptr2 [16385] i32      (65,664 alloc)
#define OFF_CUR2  92458624ull   // cursor2 [16384] i32      (65,664 alloc)
#define OFF_PRT2  92524288ull   // partials2               (4,096)
#define OFF_CSR2  92528384ull   // csr2 [262144] i32        (1,048,576)
#define OFF_WP1   93576960ull   // packed W layer1 bf16     (131,072)
#define OFF_WP2   93708032ull   // packed W layer2 bf16     (262,144)

typedef __attribute__((ext_vector_type(8))) short short8;
typedef __attribute__((ext_vector_type(4))) float f32x4;

__device__ __forceinline__ unsigned short f2bf(float f) {
    // round-to-nearest-even f32 -> bf16
    unsigned u = __float_as_uint(f);
    return (unsigned short)((u + 0x7FFFu + ((u >> 16) & 1u)) >> 16);
}
__device__ __forceinline__ float bf2f(unsigned short b) {
    return __uint_as_float(((unsigned)b) << 16);
}

// ---------------- CSR build ----------------
__global__ __launch_bounds__(256) void k_hist(const int* __restrict__ dst,
                                              int* __restrict__ cnt, int n_edges) {
    for (int e = blockIdx.x * 256 + threadIdx.x; e < n_edges; e += gridDim.x * 256)
        atomicAdd(&cnt[dst[e]], 1);
}

__global__ __launch_bounds__(256) void k_scan_part(const int* __restrict__ deg,
                                                   int* __restrict__ part, int n) {
    __shared__ int s[256];
    const int tid = threadIdx.x;
    const int gid = blockIdx.x * 256 + tid;
    s[tid] = (gid < n) ? deg[gid] : 0;
    __syncthreads();
    for (int off = 128; off > 0; off >>= 1) {
        if (tid < off) s[tid] += s[tid + off];
        __syncthreads();
    }
    if (tid == 0) part[blockIdx.x] = s[0];
}

__global__ void k_scan_mid(int* __restrict__ part, int nblk) {
    if (threadIdx.x == 0 && blockIdx.x == 0) {
        int run = 0;
        for (int b = 0; b < nblk; ++b) { int t = part[b]; part[b] = run; run += t; }
    }
}

__global__ __launch_bounds__(256) void k_scan_final(int* __restrict__ degcur,
                                                    int* __restrict__ rowptr,
                                                    const int* __restrict__ part, int n) {
    __shared__ int s[256];
    const int tid = threadIdx.x;
    const int gid = blockIdx.x * 256 + tid;
    const int v = (gid < n) ? degcur[gid] : 0;
    s[tid] = v;
    __syncthreads();
    for (int off = 1; off < 256; off <<= 1) {
        int t = (tid >= off) ? s[tid - off] : 0;
        __syncthreads();
        s[tid] += t;
        __syncthreads();
    }
    const int incl = s[tid];
    const int excl = incl - v;
    const int base = part[blockIdx.x];
    if (gid < n) { rowptr[gid] = base + excl; degcur[gid] = base + excl; }
    if (gid == n - 1) rowptr[n] = base + incl;
}

__global__ __launch_bounds__(256) void k_fill(const int* __restrict__ src,
                                              const int* __restrict__ dst,
                                              int* __restrict__ cur,
                                              int* __restrict__ csr, int n_edges) {
    for (int e = blockIdx.x * 256 + threadIdx.x; e < n_edges; e += gridDim.x * 256) {
        const int pos = atomicAdd(&cur[dst[e]], 1);
        csr[pos] = src[e];
    }
}

// ---------------- weight packing ----------------
// pack[(kb*256 + c)*32 + g*8 + j] = bf16( Wcat[kb*32 + g*8 + j][c] ),
// Wcat = concat(Wa[Keach][256], Wb[Keach][256]). One thread per (kb,c,g).
__global__ __launch_bounds__(256) void k_pack(const float* __restrict__ Wa,
                                              const float* __restrict__ Wb,
                                              int Keach, unsigned short* __restrict__ out) {
    const int t = blockIdx.x * 256 + threadIdx.x;
    const int total = (2 * Keach / 32) * 1024;
    if (t >= total) return;
    const int kb = t >> 10;
    const int c  = (t >> 2) & 255;
    const int g  = t & 3;
    const int kbase = kb * 32 + g * 8;
    const float* W = (kbase < Keach) ? (Wa + (size_t)kbase * HID + c)
                                     : (Wb + (size_t)(kbase - Keach) * HID + c);
    unsigned short* o = out + ((size_t)kb * 256 + c) * 32 + g * 8;
    #pragma unroll
    for (int j = 0; j < 8; ++j) o[j] = f2bf(W[(size_t)j * HID]);
}

// ---------------- pull aggregation (mean), bf16 output ----------------
// one wave per dst node; 64 lanes x 2 f32 cols; 4 edges in flight
__global__ __launch_bounds__(256) void k_pull_mean128(
    const float* __restrict__ x, const int* __restrict__ rp,
    const int* __restrict__ csr, unsigned int* __restrict__ msg) {
    const int d = blockIdx.x * 4 + (threadIdx.x >> 6);
    const int lane = threadIdx.x & 63;
    const int beg = rp[d], end = rp[d + 1];
    float ax = 0.0f, ay = 0.0f;
    const float* xb = x + lane * 2;
    int j = beg;
    for (; j + 3 < end; j += 4) {
        const int s0 = csr[j], s1 = csr[j + 1], s2 = csr[j + 2], s3 = csr[j + 3];
        const float2 a = *(const float2*)(xb + (size_t)s0 * IN_SIZE);
        const float2 b = *(const float2*)(xb + (size_t)s1 * IN_SIZE);
        const float2 c = *(const float2*)(xb + (size_t)s2 * IN_SIZE);
        const float2 e = *(const float2*)(xb + (size_t)s3 * IN_SIZE);
        ax += (a.x + b.x) + (c.x + e.x);
        ay += (a.y + b.y) + (c.y + e.y);
    }
    for (; j < end; ++j) {
        const float2 a = *(const float2*)(xb + (size_t)csr[j] * IN_SIZE);
        ax += a.x; ay += a.y;
    }
    const float inv = 1.0f / fmaxf((float)(end - beg), 1.0f);
    const unsigned int p = (unsigned)f2bf(ax * inv) | ((unsigned)f2bf(ay * inv) << 16);
    msg[(size_t)d * 64 + lane] = p;
}

// one wave per dst node; 64 lanes x 4 bf16 cols (gather bf16 h rows)
__global__ __launch_bounds__(256) void k_pull_mean256(
    const unsigned short* __restrict__ h, const int* __restrict__ rp,
    const int* __restrict__ csr, unsigned int* __restrict__ msg) {
    const int d = blockIdx.x * 4 + (threadIdx.x >> 6);
    const int lane = threadIdx.x & 63;
    const int beg = rp[d], end = rp[d + 1];
    float a0 = 0.f, a1 = 0.f, a2 = 0.f, a3 = 0.f;
    const unsigned short* hb = h + lane * 4;
    int j = beg;
    for (; j + 3 < end; j += 4) {
        const int s0 = csr[j], s1 = csr[j + 1], s2 = csr[j + 2], s3 = csr[j + 3];
        const uint2 va = *(const uint2*)(hb + (size_t)s0 * HID);
        const uint2 vb = *(const uint2*)(hb + (size_t)s1 * HID);
        const uint2 vc = *(const uint2*)(hb + (size_t)s2 * HID);
        const uint2 vd = *(const uint2*)(hb + (size_t)s3 * HID);
        a0 += (bf2f(va.x) + bf2f(vb.x)) + (bf2f(vc.x) + bf2f(vd.x));
        a1 += (bf2f(va.x >> 16) + bf2f(vb.x >> 16)) + (bf2f(vc.x >> 16) + bf2f(vd.x >> 16));
        a2 += (bf2f(va.y) + bf2f(vb.y)) + (bf2f(vc.y) + bf2f(vd.y));
        a3 += (bf2f(va.y >> 16) + bf2f(vb.y >> 16)) + (bf2f(vc.y >> 16) + bf2f(vd.y >> 16));
    }
    for (; j < end; ++j) {
        const uint2 va = *(const uint2*)(hb + (size_t)csr[j] * HID);
        a0 += bf2f(va.x); a1 += bf2f(va.x >> 16);
        a2 += bf2f(va.y); a3 += bf2f(va.y >> 16);
    }
    const float inv = 1.0f / fmaxf((float)(end - beg), 1.0f);
    uint2 o;
    o.x = (unsigned)f2bf(a0 * inv) | ((unsigned)f2bf(a1 * inv) << 16);
    o.y = (unsigned)f2bf(a2 * inv) | ((unsigned)f2bf(a3 * inv) << 16);
    *(uint2*)(msg + (size_t)d * 128 + lane * 2) = o;
}

// ---------------- fused MFMA GEMM ----------------
// out[i,:] = act( Acat[i,:] @ Wpack + bias ), Acat = [A1 | A2], KTOT = 2*K1.
// Block 256 thr = 4 waves; tile 32 rows x 256 cols; wave w -> cols w*64.
// Per wave: 2 row-frags x 4 col-frags of 16x16, K-steps of 32.
// mfma_f32_16x16x32_bf16; A-frag row = lane&15, k = ks*32+(lane>>4)*8+j;
// B-frag col = lane&15 (same k-map; intra-K permutation cancels);
// C/D: col = lane&15, row = (lane>>4)*4 + reg  [verified layout].
template<bool A1F32, bool OUTBF, int K1>
__global__ __launch_bounds__(256) void k_gemm_mfma(
    const void* __restrict__ A1v,           // [M][K1] f32 (A1F32) or bf16
    const unsigned short* __restrict__ A2,  // [M][K1] bf16
    const unsigned short* __restrict__ Wp,  // packed [(2*K1/32)*256*32] bf16
    const float* __restrict__ bias,         // [256] f32
    void* __restrict__ outv,                // [M][256] bf16 (OUTBF) or f32
    const int do_relu)
{
    constexpr int NKS = 2 * K1 / 32;
    const int tid  = threadIdx.x;
    const int wid  = tid >> 6;
    const int lane = tid & 63;
    const int g    = lane >> 4;
    const int r16  = lane & 15;
    const int i0   = blockIdx.x * 32;
    const int c0   = wid * 64;

    f32x4 acc[2][4];
    #pragma unroll
    for (int rb = 0; rb < 2; ++rb)
        #pragma unroll
        for (int cf = 0; cf < 4; ++cf)
            acc[rb][cf] = (f32x4){0.f, 0.f, 0.f, 0.f};

    #pragma unroll
    for (int ks = 0; ks < NKS; ++ks) {
        short8 a[2];
        #pragma unroll
        for (int rb = 0; rb < 2; ++rb) {
            const int row = i0 + rb * 16 + r16;
            const int kk  = ks * 32 + g * 8;
            if (ks < NKS / 2) {
                if (A1F32) {
                    const float* p = (const float*)A1v + (size_t)row * K1 + kk;
                    const float4 u0 = *(const float4*)(p);
                    const float4 u1 = *(const float4*)(p + 4);
                    a[rb][0] = (short)f2bf(u0.x); a[rb][1] = (short)f2bf(u0.y);
                    a[rb][2] = (short)f2bf(u0.z); a[rb][3] = (short)f2bf(u0.w);
                    a[rb][4] = (short)f2bf(u1.x); a[rb][5] = (short)f2bf(u1.y);
                    a[rb][6] = (short)f2bf(u1.z); a[rb][7] = (short)f2bf(u1.w);
                } else {
                    a[rb] = *(const short8*)((const unsigned short*)A1v + (size_t)row * K1 + kk);
                }
            } else {
                a[rb] = *(const short8*)(A2 + (size_t)row * K1 + (kk - K1));
            }
        }
        short8 b[4];
        #pragma unroll
        for (int cf = 0; cf < 4; ++cf) {
            const int col = c0 + cf * 16 + r16;
            b[cf] = *(const short8*)(Wp + ((size_t)ks * 256 + col) * 32 + g * 8);
        }
        #pragma unroll
        for (int rb = 0; rb < 2; ++rb)
            #pragma unroll
            for (int cf = 0; cf < 4; ++cf)
                acc[rb][cf] = __builtin_amdgcn_mfma_f32_16x16x32_bf16(
                    a[rb], b[cf], acc[rb][cf], 0, 0, 0);
    }

    #pragma unroll
    for (int cf = 0; cf < 4; ++cf) {
        const int col = c0 + cf * 16 + r16;
        const float bv = bias[col];
        #pragma unroll
        for (int rb = 0; rb < 2; ++rb) {
            #pragma unroll
            for (int rr = 0; rr < 4; ++rr) {
                const int row = i0 + rb * 16 + g * 4 + rr;
                float v = acc[rb][cf][rr] + bv;
                if (do_relu) v = fmaxf(v, 0.0f);
                if (OUTBF)
                    ((unsigned short*)outv)[(size_t)row * HID + col] = f2bf(v);
                else
                    ((float*)outv)[(size_t)row * HID + col] = v;
            }
        }
    }
}

extern "C" void kernel_launch(void* const* d_in, const int* in_sizes, int n_in,
                              void* d_out, int out_size, void* d_ws, size_t ws_size,
                              hipStream_t stream) {
    const float* x       = (const float*)d_in[0];
    const int*   src1    = (const int*)d_in[1];
    const int*   dst1    = (const int*)d_in[2];
    const int*   src2    = (const int*)d_in[3];
    const int*   dst2    = (const int*)d_in[4];
    const float* W_self1 = (const float*)d_in[5];
    const float* W_neigh1= (const float*)d_in[6];
    const float* b1      = (const float*)d_in[7];
    const float* W_self2 = (const float*)d_in[8];
    const float* W_neigh2= (const float*)d_in[9];
    const float* b2      = (const float*)d_in[10];
    float* out = (float*)d_out;

    char* ws = (char*)d_ws;
    unsigned short* h    = (unsigned short*)(ws + OFF_H);
    unsigned int*   msg1 = (unsigned int*)(ws + OFF_MSG1);
    unsigned int*   msg2 = (unsigned int*)(ws + OFF_MSG2);
    int* rp1  = (int*)(ws + OFF_RP1);
    int* cur1 = (int*)(ws + OFF_CUR1);
    int* prt1 = (int*)(ws + OFF_PRT1);
    int* csr1 = (int*)(ws + OFF_CSR1);
    int* rp2  = (int*)(ws + OFF_RP2);
    int* cur2 = (int*)(ws + OFF_CUR2);
    int* prt2 = (int*)(ws + OFF_PRT2);
    int* csr2 = (int*)(ws + OFF_CSR2);
    unsigned short* wp1 = (unsigned short*)(ws + OFF_WP1);
    unsigned short* wp2 = (unsigned short*)(ws + OFF_WP2);

    const int nblk1 = (N_DST1 + 255) / 256;   // 391
    const int nblk2 = (N_DST2 + 255) / 256;   // 64

    hipMemsetAsync(cur1, 0, N_DST1 * sizeof(int), stream);
    hipMemsetAsync(cur2, 0, N_DST2 * sizeof(int), stream);
    k_pack<<<32, 256, 0, stream>>>(W_self1, W_neigh1, 128, wp1);
    k_pack<<<64, 256, 0, stream>>>(W_self2, W_neigh2, 256, wp2);

    // ---- layer 1 ----
    k_hist<<<2048, 256, 0, stream>>>(dst1, cur1, E1);
    k_scan_part<<<nblk1, 256, 0, stream>>>(cur1, prt1, N_DST1);
    k_scan_mid<<<1, 64, 0, stream>>>(prt1, nblk1);
    k_scan_final<<<nblk1, 256, 0, stream>>>(cur1, rp1, prt1, N_DST1);
    k_fill<<<2048, 256, 0, stream>>>(src1, dst1, cur1, csr1, E1);
    k_pull_mean128<<<N_DST1 / 4, 256, 0, stream>>>(x, rp1, csr1, msg1);
    k_gemm_mfma<true, true, IN_SIZE><<<N_DST1 / 32, 256, 0, stream>>>(
        x, (const unsigned short*)msg1, wp1, b1, h, 1);

    // ---- layer 2 ----
    k_hist<<<1024, 256, 0, stream>>>(dst2, cur2, E2);
    k_scan_part<<<nblk2, 256, 0, stream>>>(cur2, prt2, N_DST2);
    k_scan_mid<<<1, 64, 0, stream>>>(prt2, nblk2);
    k_scan_final<<<nblk2, 256, 0, stream>>>(cur2, rp2, prt2, N_DST2);
    k_fill<<<1024, 256, 0, stream>>>(src2, dst2, cur2, csr2, E2);
    k_pull_mean256<<<N_DST2 / 4, 256, 0, stream>>>(h, rp2, csr2, msg2);
    k_gemm_mfma<false, false, HID><<<N_DST2 / 32, 256, 0, stream>>>(
        h, (const unsigned short*)msg2, wp2, b2, out, 0);
}

// Round 4
// 449.572 us; speedup vs baseline: 5.6315x; 1.2198x over previous
//
#include <hip/hip_runtime.h>

#define IN_SIZE 128
#define HID 256
#define N_SRC1 500000
#define N_DST1 100000
#define E1 1600000
#define N_DST2 16384
#define E2 262144

// ---------------- workspace layout (bytes), total 162,377,216 ----------------
// xbf [500000][128] bf16 @ 0 (128,000,000)      live: prep -> gemm1
// h   [100000][256] bf16 @ 76,800,000 (51.2MB)  aliases xbf rows 300K..500K,
//                                               written by gemm1 (xbf tail dead)
// msg1 [100000][128] bf16 @ 128,000,000 (25.6MB)
// CSR + weights @ 153,600,000
#define OFF_XBF  0ull
#define OFF_H    76800000ull
#define OFF_MSG1 128000000ull
#define OFF_RP1  153600000ull   // [100001] i32 (400,128 alloc)
#define OFF_RP2  154000128ull   // [16385] i32  (65,664 alloc)
#define OFF_CUR1 154065792ull   // [100000] i32 (400,000)
#define OFF_CUR2 154465792ull   // [16384] i32  (65,536)   cur1+cur2 one memset
#define OFF_PRT1 154531328ull   // (2,048)
#define OFF_PRT2 154533376ull   // (2,048)
#define OFF_CSR1 154535424ull   // [1,600,000] i32 (6,400,000)
#define OFF_CSR2 160935424ull   // [262,144] i32 (1,048,576)
#define OFF_WP1  161984000ull   // packed W1 bf16 (131,072)
#define OFF_WP2  162115072ull   // packed W2 bf16 (262,144)

typedef __attribute__((ext_vector_type(8))) short short8;
typedef __attribute__((ext_vector_type(4))) float f32x4;

__device__ __forceinline__ unsigned short f2bf(float f) {
    unsigned u = __float_as_uint(f);
    return (unsigned short)((u + 0x7FFFu + ((u >> 16) & 1u)) >> 16);
}
__device__ __forceinline__ float bf2f(unsigned short b) {
    return __uint_as_float(((unsigned)b) << 16);
}

// ---------------- prep: cast x -> bf16, plus both histograms ----------------
__global__ __launch_bounds__(256) void k_prep(
    const float* __restrict__ x, unsigned short* __restrict__ xbf,
    const int* __restrict__ dst1, int* __restrict__ cur1,
    const int* __restrict__ dst2, int* __restrict__ cur2)
{
    const int T = gridDim.x * 256;
    const int tid = blockIdx.x * 256 + threadIdx.x;
    // cast: 8M chunks of 8 floats
    const float4* x4 = (const float4*)x;
    short8* o8 = (short8*)xbf;
    for (int i = tid; i < N_SRC1 * IN_SIZE / 8; i += T) {
        const float4 u0 = x4[(size_t)i * 2];
        const float4 u1 = x4[(size_t)i * 2 + 1];
        short8 o;
        o[0] = (short)f2bf(u0.x); o[1] = (short)f2bf(u0.y);
        o[2] = (short)f2bf(u0.z); o[3] = (short)f2bf(u0.w);
        o[4] = (short)f2bf(u1.x); o[5] = (short)f2bf(u1.y);
        o[6] = (short)f2bf(u1.z); o[7] = (short)f2bf(u1.w);
        o8[i] = o;
    }
    for (int e = tid; e < E1; e += T) atomicAdd(&cur1[dst1[e]], 1);
    for (int e = tid; e < E2; e += T) atomicAdd(&cur2[dst2[e]], 1);
}

// ---------------- CSR build (both layers share kernels) ----------------
__global__ __launch_bounds__(256) void k_scan_part(
    const int* __restrict__ cur1, int* __restrict__ prt1,
    const int* __restrict__ cur2, int* __restrict__ prt2, int nblk1)
{
    __shared__ int s[256];
    const int tid = threadIdx.x;
    const int l1 = (int)blockIdx.x < nblk1;
    const int b = l1 ? blockIdx.x : blockIdx.x - nblk1;
    const int n = l1 ? N_DST1 : N_DST2;
    const int* deg = l1 ? cur1 : cur2;
    int* part = l1 ? prt1 : prt2;
    const int gid = b * 256 + tid;
    s[tid] = (gid < n) ? deg[gid] : 0;
    __syncthreads();
    for (int off = 128; off > 0; off >>= 1) {
        if (tid < off) s[tid] += s[tid + off];
        __syncthreads();
    }
    if (tid == 0) part[b] = s[0];
}

// parallel exclusive scan of both partial arrays (block 0 -> prt1, 1 -> prt2)
__global__ __launch_bounds__(512) void k_scan_mid(
    int* __restrict__ prt1, int n1, int* __restrict__ prt2, int n2)
{
    __shared__ int s[512];
    int* p = (blockIdx.x == 0) ? prt1 : prt2;
    const int n = (blockIdx.x == 0) ? n1 : n2;
    const int tid = threadIdx.x;
    const int v = (tid < n) ? p[tid] : 0;
    s[tid] = v;
    __syncthreads();
    for (int off = 1; off < 512; off <<= 1) {
        int t = (tid >= off) ? s[tid - off] : 0;
        __syncthreads();
        s[tid] += t;
        __syncthreads();
    }
    if (tid < n) p[tid] = s[tid] - v;   // exclusive
}

__global__ __launch_bounds__(256) void k_scan_final(
    int* __restrict__ cur1, int* __restrict__ rp1, const int* __restrict__ prt1,
    int* __restrict__ cur2, int* __restrict__ rp2, const int* __restrict__ prt2,
    int nblk1)
{
    __shared__ int s[256];
    const int tid = threadIdx.x;
    const int l1 = (int)blockIdx.x < nblk1;
    const int b = l1 ? blockIdx.x : blockIdx.x - nblk1;
    const int n = l1 ? N_DST1 : N_DST2;
    int* degcur = l1 ? cur1 : cur2;
    int* rowptr = l1 ? rp1 : rp2;
    const int* part = l1 ? prt1 : prt2;
    const int gid = b * 256 + tid;
    const int v = (gid < n) ? degcur[gid] : 0;
    s[tid] = v;
    __syncthreads();
    for (int off = 1; off < 256; off <<= 1) {
        int t = (tid >= off) ? s[tid - off] : 0;
        __syncthreads();
        s[tid] += t;
        __syncthreads();
    }
    const int excl = s[tid] - v;
    const int base = part[b];
    if (gid < n) { rowptr[gid] = base + excl; degcur[gid] = base + excl; }
    if (gid == n - 1) rowptr[n] = base + s[tid];
}

__global__ __launch_bounds__(256) void k_fill(
    const int* __restrict__ src1, const int* __restrict__ dst1,
    int* __restrict__ cur1, int* __restrict__ csr1,
    const int* __restrict__ src2, const int* __restrict__ dst2,
    int* __restrict__ cur2, int* __restrict__ csr2)
{
    if (blockIdx.x < 2048) {
        const int T = 2048 * 256;
        for (int e = blockIdx.x * 256 + threadIdx.x; e < E1; e += T) {
            const int pos = atomicAdd(&cur1[dst1[e]], 1);
            csr1[pos] = src1[e];
        }
    } else {
        const int T = 1024 * 256;
        for (int e = (blockIdx.x - 2048) * 256 + threadIdx.x; e < E2; e += T) {
            const int pos = atomicAdd(&cur2[dst2[e]], 1);
            csr2[pos] = src2[e];
        }
    }
}

// ---------------- weight packing ----------------
// pack[(kb*256 + c)*32 + g*8 + j] = bf16( Wcat[kb*32 + g*8 + j][c] )
__global__ __launch_bounds__(256) void k_pack(const float* __restrict__ Wa,
                                              const float* __restrict__ Wb,
                                              int Keach, unsigned short* __restrict__ out) {
    const int t = blockIdx.x * 256 + threadIdx.x;
    const int total = (2 * Keach / 32) * 1024;
    if (t >= total) return;
    const int kb = t >> 10;
    const int c  = (t >> 2) & 255;
    const int g  = t & 3;
    const int kbase = kb * 32 + g * 8;
    const float* W = (kbase < Keach) ? (Wa + (size_t)kbase * HID + c)
                                     : (Wb + (size_t)(kbase - Keach) * HID + c);
    unsigned short* o = out + ((size_t)kb * 256 + c) * 32 + g * 8;
    #pragma unroll
    for (int j = 0; j < 8; ++j) o[j] = f2bf(W[(size_t)j * HID]);
}

// ---------------- layer-1 pull (bf16 gather, half-wave per dst) ----------------
// 8 dst/block; 32 lanes per dst, lane loads uint2 = 4 bf16 cols (128 cols)
__global__ __launch_bounds__(256) void k_pull1(
    const unsigned short* __restrict__ xbf, const int* __restrict__ rp,
    const int* __restrict__ csr, unsigned short* __restrict__ msg)
{
    const int d = blockIdx.x * 8 + (threadIdx.x >> 5);
    const int hl = threadIdx.x & 31;
    const int beg = rp[d], end = rp[d + 1];
    float a0 = 0.f, a1 = 0.f, a2 = 0.f, a3 = 0.f;
    const unsigned short* xb = xbf + hl * 4;
    int j = beg;
    for (; j + 3 < end; j += 4) {
        const int s0 = csr[j], s1 = csr[j + 1], s2 = csr[j + 2], s3 = csr[j + 3];
        const uint2 va = *(const uint2*)(xb + (size_t)s0 * IN_SIZE);
        const uint2 vb = *(const uint2*)(xb + (size_t)s1 * IN_SIZE);
        const uint2 vc = *(const uint2*)(xb + (size_t)s2 * IN_SIZE);
        const uint2 vd = *(const uint2*)(xb + (size_t)s3 * IN_SIZE);
        a0 += (bf2f(va.x) + bf2f(vb.x)) + (bf2f(vc.x) + bf2f(vd.x));
        a1 += (bf2f(va.x >> 16) + bf2f(vb.x >> 16)) + (bf2f(vc.x >> 16) + bf2f(vd.x >> 16));
        a2 += (bf2f(va.y) + bf2f(vb.y)) + (bf2f(vc.y) + bf2f(vd.y));
        a3 += (bf2f(va.y >> 16) + bf2f(vb.y >> 16)) + (bf2f(vc.y >> 16) + bf2f(vd.y >> 16));
    }
    for (; j < end; ++j) {
        const uint2 va = *(const uint2*)(xb + (size_t)csr[j] * IN_SIZE);
        a0 += bf2f(va.x); a1 += bf2f(va.x >> 16);
        a2 += bf2f(va.y); a3 += bf2f(va.y >> 16);
    }
    const float inv = 1.0f / fmaxf((float)(end - beg), 1.0f);
    uint2 o;
    o.x = (unsigned)f2bf(a0 * inv) | ((unsigned)f2bf(a1 * inv) << 16);
    o.y = (unsigned)f2bf(a2 * inv) | ((unsigned)f2bf(a3 * inv) << 16);
    *(uint2*)(msg + (size_t)d * IN_SIZE + hl * 4) = o;
}

// ---------------- layer-1 MFMA GEMM ----------------
// h[i,:] = relu( [xbf | msg1][i,:] @ Wp1 + b1 ), all-bf16 A operands.
__global__ __launch_bounds__(256) void k_gemm1(
    const unsigned short* __restrict__ A1,  // xbf [M][128]
    const unsigned short* __restrict__ A2,  // msg1 [M][128]
    const unsigned short* __restrict__ Wp,
    const float* __restrict__ bias,
    unsigned short* __restrict__ out)       // h bf16 [M][256]
{
    constexpr int NKS = 8;
    const int tid = threadIdx.x;
    const int wid = tid >> 6;
    const int lane = tid & 63;
    const int g = lane >> 4, r16 = lane & 15;
    const int i0 = blockIdx.x * 32;
    const int c0 = wid * 64;

    f32x4 acc[2][4];
    #pragma unroll
    for (int rb = 0; rb < 2; ++rb)
        #pragma unroll
        for (int cf = 0; cf < 4; ++cf)
            acc[rb][cf] = (f32x4){0.f, 0.f, 0.f, 0.f};

    #pragma unroll
    for (int ks = 0; ks < NKS; ++ks) {
        short8 a[2];
        #pragma unroll
        for (int rb = 0; rb < 2; ++rb) {
            const int row = i0 + rb * 16 + r16;
            const int kk = ks * 32 + g * 8;
            a[rb] = (ks < NKS / 2)
                ? *(const short8*)(A1 + (size_t)row * IN_SIZE + kk)
                : *(const short8*)(A2 + (size_t)row * IN_SIZE + (kk - IN_SIZE));
        }
        short8 b[4];
        #pragma unroll
        for (int cf = 0; cf < 4; ++cf) {
            const int col = c0 + cf * 16 + r16;
            b[cf] = *(const short8*)(Wp + ((size_t)ks * 256 + col) * 32 + g * 8);
        }
        #pragma unroll
        for (int rb = 0; rb < 2; ++rb)
            #pragma unroll
            for (int cf = 0; cf < 4; ++cf)
                acc[rb][cf] = __builtin_amdgcn_mfma_f32_16x16x32_bf16(
                    a[rb], b[cf], acc[rb][cf], 0, 0, 0);
    }

    #pragma unroll
    for (int cf = 0; cf < 4; ++cf) {
        const int col = c0 + cf * 16 + r16;
        const float bv = bias[col];
        #pragma unroll
        for (int rb = 0; rb < 2; ++rb)
            #pragma unroll
            for (int rr = 0; rr < 4; ++rr) {
                const int row = i0 + rb * 16 + g * 4 + rr;
                out[(size_t)row * HID + col] = f2bf(fmaxf(acc[rb][cf][rr] + bv, 0.0f));
            }
    }
}

// ---------------- layer-2 fused pull + MFMA GEMM ----------------
// out[i,:] = [h | mean_agg(h)][i,:] @ Wp2 + b2, f32 out. 32 rows/block.
__global__ __launch_bounds__(256) void k_sage2(
    const unsigned short* __restrict__ h,   // [N_DST1][256] bf16
    const int* __restrict__ rp, const int* __restrict__ csr,
    const unsigned short* __restrict__ Wp,
    const float* __restrict__ bias,
    float* __restrict__ out)                // [N_DST2][256] f32
{
    __shared__ __align__(16) unsigned short At[32][264];  // +8 pad: 2-way banks max
    const int tid = threadIdx.x;
    const int wid = tid >> 6;
    const int lane = tid & 63;
    const int i0 = blockIdx.x * 32;

    // phase A: wave wid aggregates rows wid*8 .. wid*8+7 (lane = 4 cols)
    for (int r = 0; r < 8; ++r) {
        const int row = wid * 8 + r;
        const int d = i0 + row;
        const int beg = rp[d], end = rp[d + 1];
        float a0 = 0.f, a1 = 0.f, a2 = 0.f, a3 = 0.f;
        const unsigned short* hb = h + lane * 4;
        int j = beg;
        for (; j + 3 < end; j += 4) {
            const int s0 = csr[j], s1 = csr[j + 1], s2 = csr[j + 2], s3 = csr[j + 3];
            const uint2 va = *(const uint2*)(hb + (size_t)s0 * HID);
            const uint2 vb = *(const uint2*)(hb + (size_t)s1 * HID);
            const uint2 vc = *(const uint2*)(hb + (size_t)s2 * HID);
            const uint2 vd = *(const uint2*)(hb + (size_t)s3 * HID);
            a0 += (bf2f(va.x) + bf2f(vb.x)) + (bf2f(vc.x) + bf2f(vd.x));
            a1 += (bf2f(va.x >> 16) + bf2f(vb.x >> 16)) + (bf2f(vc.x >> 16) + bf2f(vd.x >> 16));
            a2 += (bf2f(va.y) + bf2f(vb.y)) + (bf2f(vc.y) + bf2f(vd.y));
            a3 += (bf2f(va.y >> 16) + bf2f(vb.y >> 16)) + (bf2f(vc.y >> 16) + bf2f(vd.y >> 16));
        }
        for (; j < end; ++j) {
            const uint2 va = *(const uint2*)(hb + (size_t)csr[j] * HID);
            a0 += bf2f(va.x); a1 += bf2f(va.x >> 16);
            a2 += bf2f(va.y); a3 += bf2f(va.y >> 16);
        }
        const float inv = 1.0f / fmaxf((float)(end - beg), 1.0f);
        uint2 o;
        o.x = (unsigned)f2bf(a0 * inv) | ((unsigned)f2bf(a1 * inv) << 16);
        o.y = (unsigned)f2bf(a2 * inv) | ((unsigned)f2bf(a3 * inv) << 16);
        *(uint2*)&At[row][lane * 4] = o;
    }
    __syncthreads();

    // phase B: MFMA. KTOT=512: first 8 K-steps self (h global), last 8 agg (LDS)
    const int g = lane >> 4, r16 = lane & 15;
    const int c0 = wid * 64;
    f32x4 acc[2][4];
    #pragma unroll
    for (int rb = 0; rb < 2; ++rb)
        #pragma unroll
        for (int cf = 0; cf < 4; ++cf)
            acc[rb][cf] = (f32x4){0.f, 0.f, 0.f, 0.f};

    #pragma unroll
    for (int ks = 0; ks < 16; ++ks) {
        short8 a[2];
        #pragma unroll
        for (int rb = 0; rb < 2; ++rb) {
            const int row16 = rb * 16 + r16;
            if (ks < 8)
                a[rb] = *(const short8*)(h + (size_t)(i0 + row16) * HID + ks * 32 + g * 8);
            else
                a[rb] = *(const short8*)&At[row16][(ks - 8) * 32 + g * 8];
        }
        short8 b[4];
        #pragma unroll
        for (int cf = 0; cf < 4; ++cf) {
            const int col = c0 + cf * 16 + r16;
            b[cf] = *(const short8*)(Wp + ((size_t)ks * 256 + col) * 32 + g * 8);
        }
        #pragma unroll
        for (int rb = 0; rb < 2; ++rb)
            #pragma unroll
            for (int cf = 0; cf < 4; ++cf)
                acc[rb][cf] = __builtin_amdgcn_mfma_f32_16x16x32_bf16(
                    a[rb], b[cf], acc[rb][cf], 0, 0, 0);
    }

    #pragma unroll
    for (int cf = 0; cf < 4; ++cf) {
        const int col = c0 + cf * 16 + r16;
        const float bv = bias[col];
        #pragma unroll
        for (int rb = 0; rb < 2; ++rb)
            #pragma unroll
            for (int rr = 0; rr < 4; ++rr) {
                const int row = i0 + rb * 16 + g * 4 + rr;
                out[(size_t)row * HID + col] = acc[rb][cf][rr] + bv;
            }
    }
}

extern "C" void kernel_launch(void* const* d_in, const int* in_sizes, int n_in,
                              void* d_out, int out_size, void* d_ws, size_t ws_size,
                              hipStream_t stream) {
    const float* x       = (const float*)d_in[0];
    const int*   src1    = (const int*)d_in[1];
    const int*   dst1    = (const int*)d_in[2];
    const int*   src2    = (const int*)d_in[3];
    const int*   dst2    = (const int*)d_in[4];
    const float* W_self1 = (const float*)d_in[5];
    const float* W_neigh1= (const float*)d_in[6];
    const float* b1      = (const float*)d_in[7];
    const float* W_self2 = (const float*)d_in[8];
    const float* W_neigh2= (const float*)d_in[9];
    const float* b2      = (const float*)d_in[10];
    float* out = (float*)d_out;

    char* ws = (char*)d_ws;
    unsigned short* xbf  = (unsigned short*)(ws + OFF_XBF);
    unsigned short* h    = (unsigned short*)(ws + OFF_H);
    unsigned short* msg1 = (unsigned short*)(ws + OFF_MSG1);
    int* rp1  = (int*)(ws + OFF_RP1);
    int* rp2  = (int*)(ws + OFF_RP2);
    int* cur1 = (int*)(ws + OFF_CUR1);
    int* cur2 = (int*)(ws + OFF_CUR2);
    int* prt1 = (int*)(ws + OFF_PRT1);
    int* prt2 = (int*)(ws + OFF_PRT2);
    int* csr1 = (int*)(ws + OFF_CSR1);
    int* csr2 = (int*)(ws + OFF_CSR2);
    unsigned short* wp1 = (unsigned short*)(ws + OFF_WP1);
    unsigned short* wp2 = (unsigned short*)(ws + OFF_WP2);

    const int nblk1 = (N_DST1 + 255) / 256;   // 391
    const int nblk2 = (N_DST2 + 255) / 256;   // 64

    // zero cur1+cur2 (contiguous) in one memset
    hipMemsetAsync(cur1, 0, 465536, stream);

    k_pack<<<32, 256, 0, stream>>>(W_self1, W_neigh1, 128, wp1);
    k_pack<<<64, 256, 0, stream>>>(W_self2, W_neigh2, 256, wp2);

    k_prep<<<2048, 256, 0, stream>>>(x, xbf, dst1, cur1, dst2, cur2);
    k_scan_part<<<nblk1 + nblk2, 256, 0, stream>>>(cur1, prt1, cur2, prt2, nblk1);
    k_scan_mid<<<2, 512, 0, stream>>>(prt1, nblk1, prt2, nblk2);
    k_scan_final<<<nblk1 + nblk2, 256, 0, stream>>>(cur1, rp1, prt1, cur2, rp2, prt2, nblk1);
    k_fill<<<3072, 256, 0, stream>>>(src1, dst1, cur1, csr1, src2, dst2, cur2, csr2);

    k_pull1<<<N_DST1 / 8, 256, 0, stream>>>(xbf, rp1, csr1, msg1);
    k_gemm1<<<N_DST1 / 32, 256, 0, stream>>>(xbf, msg1, wp1, b1, h);
    k_sage2<<<N_DST2 / 32, 256, 0, stream>>>(h, rp2, csr2, wp2, b2, out);
}